// Round 11
// baseline (379.982 us; speedup 1.0000x reference)
//
#include <hip/hip_runtime.h>
#include <stdint.h>

// ---- PRNG mode: 1 = jax_threefry_partitionable (default in jax >= 0.5)
#ifndef PRNG_PARTITIONABLE
#define PRNG_PARTITIONABLE 1
#endif

#define ONE_M_U 0.99999994039535522461f   // 1 - 2^-24 (0x3F7FFFFF)

// ---------------- threefry2x32 (exact JAX rounds) ----------------
__device__ __forceinline__ void tf_4a(uint32_t& x0, uint32_t& x1){
  x0 += x1; x1 = (x1<<13)|(x1>>19); x1 ^= x0;
  x0 += x1; x1 = (x1<<15)|(x1>>17); x1 ^= x0;
  x0 += x1; x1 = (x1<<26)|(x1>>6);  x1 ^= x0;
  x0 += x1; x1 = (x1<<6) |(x1>>26); x1 ^= x0;
}
__device__ __forceinline__ void tf_4b(uint32_t& x0, uint32_t& x1){
  x0 += x1; x1 = (x1<<17)|(x1>>15); x1 ^= x0;
  x0 += x1; x1 = (x1<<29)|(x1>>3);  x1 ^= x0;
  x0 += x1; x1 = (x1<<16)|(x1>>16); x1 ^= x0;
  x0 += x1; x1 = (x1<<24)|(x1>>8);  x1 ^= x0;
}
__device__ __forceinline__ void threefry2x32(uint32_t k0, uint32_t k1, uint32_t& x0, uint32_t& x1){
  uint32_t k2 = k0 ^ k1 ^ 0x1BD11BDAu;
  x0 += k0; x1 += k1;
  tf_4a(x0,x1); x0 += k1; x1 += k2 + 1u;
  tf_4b(x0,x1); x0 += k2; x1 += k0 + 2u;
  tf_4a(x0,x1); x0 += k0; x1 += k1 + 3u;
  tf_4b(x0,x1); x0 += k1; x1 += k2 + 4u;
  tf_4a(x0,x1); x0 += k2; x1 += k0 + 5u;
}

__device__ __forceinline__ float bits_to_unit(uint32_t b){
  #pragma clang fp contract(off)
  float f = __uint_as_float((b >> 9) | 0x3f800000u) - 1.0f;
  float r = f * 2.0f + (-1.0f);
  return __builtin_fmaxf(-1.0f, r);
}

// XLA elemental_ir_emitter EmitTanh f32 (unfused mul/add)
__device__ __forceinline__ float xla_tanh_f32(float x){
  #pragma clang fp contract(off)
  float ax = __builtin_fabsf(x);
  float xc = __builtin_fminf(__builtin_fmaxf(x, -9.0f), 9.0f);
  float x2 = xc * xc;
  float nm = -2.76076847742355e-16f;
  nm = x2 * nm + 2.00018790482477e-13f;
  nm = x2 * nm + -8.60467152213735e-11f;
  nm = x2 * nm + 5.12229709037114e-08f;
  nm = x2 * nm + 1.48572235717979e-05f;
  nm = x2 * nm + 6.37261928875436e-04f;
  nm = x2 * nm + 4.89352455891786e-03f;
  nm = xc * nm;
  float dn = 1.19825839466702e-06f;
  dn = x2 * dn + 1.18534705686654e-04f;
  dn = x2 * dn + 2.26843463243900e-03f;
  dn = x2 * dn + 4.89352518554385e-03f;
  float res = nm / dn;
  return (ax < 0.0004f) ? x : res;
}

// k-ascending fma chain (fallback path only)
__device__ __forceinline__ float dot64(unsigned long long sw, unsigned long long dw,
                                       const float* w){
  float acc = 0.0f;
  #pragma unroll
  for (int k = 0; k < 64; ++k){
    float mag = ((dw >> k) & 1ull) ? ONE_M_U : 1.0f;
    float p   = ((sw >> k) & 1ull) ? mag : -mag;
    acc = __builtin_fmaf(p, w[k], acc);
  }
  return acc;
}

// -------- workspace layout (bytes) --------
#define QW_OFF   0u           // float[9][128][64]   ([g][o][k])
#define SGN_OFF  294912u      // u64[32][9][1024]
#define DIM_OFF  2654208u     // u64[32][9][1024]
#define KEYS_OFF 5013504u     // u32[18]
#define MV_OFF   5013632u     // float[9*128][2]
#define LT_OFF   5023744u     // float[32][9][128][1024]  (fast path)
#define LT_BYTES 150994944u
#define PART_OFF  (LT_OFF + LT_BYTES)       // double[9*128][256]  (sum tv partials)
#define PART_BYTES 2359296u
#define PART2_OFF (PART_OFF + PART_BYTES)   // double[9*128][256]  (sum tv^2 partials)
#define WS_NEEDED_FAST (PART2_OFF + PART_BYTES)

// ================= K_FRONT: blocks 0..287 = stream, 288..415 = weights+keys ========
__global__ __launch_bounds__(256) void k_front(const float* __restrict__ X,
        const float* __restrict__ W, float* __restrict__ qw, uint32_t* __restrict__ keys,
        unsigned long long* __restrict__ sgn, unsigned long long* __restrict__ dimw){
  #pragma clang fp contract(off)
  __shared__ float  bwL[576];
  __shared__ double red[64];
  int bx = blockIdx.x;
  int t = threadIdx.x;
  if (bx < 288){
    // ---- stream path (identical per-thread work to verified k_stream) ----
    int g = bx >> 5;                       // 0..8, block-uniform
    int tid = (bx & 31) * 256 + t;         // 0..8191
    int b = tid >> 10, l = tid & 1023;
    int h = l >> 5, w = l & 31;
    unsigned long long sw0=0ull, sw1=0ull, sw2=0ull, sw3=0ull;
    unsigned long long dw0=0ull, dw1=0ull, dw2=0ull, dw3=0ull;
    const float* Xb = X + b*64*1024;
    int ck0 = g*64;
    #pragma unroll
    for (int i = 0; i < 64; ++i){
      int ck = ck0 + i;
      int c = ck / 9, kp = ck % 9;          // block-uniform -> scalar
      int di = kp / 3 - 1, dj = kp % 3 - 1;
      int hh = h + di, ww = w + dj;
      float v = 0.0f;
      if (hh >= 0 && hh < 32 && ww >= 0 && ww < 32)
        v = Xb[(c*32 + hh)*32 + ww];
      float x = __builtin_fminf(__builtin_fmaxf(v, -1.0f), 1.0f);
      float r = x;
      {
        float sv = (r >= 0.0f) ? 1.0f : -1.0f;
        float d  = sv - x; float p = x + d;
        if (sv > 0.0f) sw0 |= (1ull << i);
        if (__builtin_fabsf(p) < 1.0f) dw0 |= (1ull << i);
        r = r - sv * 0.5f;
      }
      {
        float sv = (r >= 0.0f) ? 1.0f : -1.0f;
        float d  = sv - x; float p = x + d;
        if (sv > 0.0f) sw1 |= (1ull << i);
        if (__builtin_fabsf(p) < 1.0f) dw1 |= (1ull << i);
        r = r - sv * 0.25f;
      }
      {
        float sv = (r >= 0.0f) ? 1.0f : -1.0f;
        float d  = sv - x; float p = x + d;
        if (sv > 0.0f) sw2 |= (1ull << i);
        if (__builtin_fabsf(p) < 1.0f) dw2 |= (1ull << i);
        r = r - sv * 0.125f;
      }
      {
        float sv = (r >= 0.0f) ? 1.0f : -1.0f;
        float d  = sv - x; float p = x + d;
        if (sv > 0.0f) sw3 |= (1ull << i);
        if (__builtin_fabsf(p) < 1.0f) dw3 |= (1ull << i);
        r = r - sv * 0.0625f;
      }
    }
    sgn [((0*8+b)*9 + g)*1024 + l] = sw0;
    sgn [((1*8+b)*9 + g)*1024 + l] = sw1;
    sgn [((2*8+b)*9 + g)*1024 + l] = sw2;
    sgn [((3*8+b)*9 + g)*1024 + l] = sw3;
    dimw[((0*8+b)*9 + g)*1024 + l] = dw0;
    dimw[((1*8+b)*9 + g)*1024 + l] = dw1;
    dimw[((2*8+b)*9 + g)*1024 + l] = dw2;
    dimw[((3*8+b)*9 + g)*1024 + l] = dw3;
  } else {
    // ---- weights path: o = bx-288; f64 reductions use the verified 64-thread order
    int o = bx - 288;
    if (t < 64){
      double s = 0.0;
      for (int j = t; j < 576; j += 64) s += (double)W[o*576 + j];
      red[t] = s;
    }
    __syncthreads();
    for (int k = 32; k > 0; k >>= 1){ if (t < k) red[t] += red[t+k]; __syncthreads(); }
    float mean1 = (float)(red[0] / 576.0);
    __syncthreads();
    for (int j = t; j < 576; j += 256) bwL[j] = W[o*576 + j] - mean1;   // elementwise, exact
    __syncthreads();
    if (t < 64){
      double s = 0.0;
      for (int j = t; j < 576; j += 64) s += (double)bwL[j];
      red[t] = s;
    }
    __syncthreads();
    for (int k = 32; k > 0; k >>= 1){ if (t < k) red[t] += red[t+k]; __syncthreads(); }
    float mean2 = (float)(red[0] / 576.0);
    __syncthreads();
    if (t < 64){
      double s = 0.0;
      for (int j = t; j < 576; j += 64){ float c = bwL[j] - mean2; float sq = c * c; s += (double)sq; }
      red[t] = s;
    }
    __syncthreads();
    for (int k = 32; k > 0; k >>= 1){ if (t < k) red[t] += red[t+k]; __syncthreads(); }
    float varf = (float)(red[0] / 575.0);
    float stdv = __builtin_sqrtf(varf);
    __syncthreads();
    for (int j = t; j < 576; j += 256){       // elementwise, exact
      float b2 = bwL[j] / stdv;
      float c  = __builtin_fminf(__builtin_fmaxf(b2, -1.0f), 1.0f);
      float q  = __builtin_rintf(c * 7.0f) / 7.0f;
      float fwd = c + (q - c);
      int g = j >> 6, k = j & 63;
      qw [(g*128 + o)*64 + k] = fwd;
    }
    if (o == 0 && t == 0){
#if PRNG_PARTITIONABLE
      for (int g = 0; g < 9; ++g){
        uint32_t x0 = 0u, x1 = (uint32_t)g;
        threefry2x32(0u, 42u, x0, x1);
        keys[2*g] = x0; keys[2*g+1] = x1;
      }
#else
      uint32_t outv[18];
      for (int i = 0; i < 9; ++i){
        uint32_t x0 = (uint32_t)i, x1 = (uint32_t)(9 + i);
        threefry2x32(0u, 42u, x0, x1);
        outv[i] = x0; outv[9+i] = x1;
      }
      for (int j = 0; j < 18; ++j) keys[j] = outv[j];
#endif
    }
  }
}

// ================= K_GEMM v7: v5 tiles + halved pS (two 64-l passes) ===============
// LDS 34.8 KB -> 4 blocks/CU. grid (16, 9, 32): bx = lq(0..7) + 8*oh(0..1).
// Thread (ot,ltl) covers the SAME 8 l's (ltl+16j, j=0..7) with the SAME k-ascending
// 0..63 FMA chain and SAME j-ascending f64 partial order as r10 -> lt/part/part2
// bit-identical.
__global__ __launch_bounds__(256) void k_gemm(const float* __restrict__ qw,
        const unsigned long long* __restrict__ sgn, const unsigned long long* __restrict__ dimw,
        float* __restrict__ lt, double* __restrict__ part, double* __restrict__ part2){
  __shared__ float4 wS[64*17];    // 17408 B: wS[oo*17+kq] = w[g][oh*64+oo][4kq..]
  __shared__ float4 pS[64*17];    // 17408 B: one 64-l half; reused as f64 red (8 KB)
  int bx = blockIdx.x, g = blockIdx.y, n = blockIdx.z;
  int lq = bx & 7, oh = bx >> 3;
  int t = threadIdx.x;
  // stage w (64 o rows)
  {
    int orow = t >> 4, kq = t & 15;
    const float4* qw4 = (const float4*)qw;
    #pragma unroll
    for (int i = 0; i < 4; ++i){
      int oo = orow + 16*i;
      wS[oo*17 + kq] = qw4[(g*128 + oh*64 + oo)*16 + kq];
    }
  }
  int ot = t >> 4, ltl = t & 15;     // o = oh*64 + ot*4 + i
  float acc[4][8];
  #pragma unroll
  for (int i = 0; i < 4; ++i)
    #pragma unroll
    for (int j = 0; j < 8; ++j) acc[i][j] = 0.0f;
  // bitmask load for decode role: thread t -> l-half-local l2 = t>>2, kgroup = t&3
  int l2 = t >> 2, kg = t & 3;
  #pragma unroll
  for (int half = 0; half < 2; ++half){
    if (half) __syncthreads();       // pS fully read before re-decode
    // decode 64 l of this half
    {
      int lfull = lq*128 + half*64 + l2;
      unsigned long long sw = sgn [(n*9+g)*1024 + lfull];
      unsigned long long dw = dimw[(n*9+g)*1024 + lfull];
      #pragma unroll
      for (int q = 0; q < 4; ++q){
        int kq = kg*4 + q;
        int k = kq*4;
        float4 v;
        float m0 = ((dw>>k)&1ull)?ONE_M_U:1.0f;     v.x = ((sw>>k)&1ull)?m0:-m0;
        float m1 = ((dw>>(k+1))&1ull)?ONE_M_U:1.0f; v.y = ((sw>>(k+1))&1ull)?m1:-m1;
        float m2 = ((dw>>(k+2))&1ull)?ONE_M_U:1.0f; v.z = ((sw>>(k+2))&1ull)?m2:-m2;
        float m3 = ((dw>>(k+3))&1ull)?ONE_M_U:1.0f; v.w = ((sw>>(k+3))&1ull)?m3:-m3;
        pS[l2*17 + kq] = v;
      }
    }
    __syncthreads();
    // FMA over this half's 4 j-columns (j_global = half*4 + jj)
    for (int kq = 0; kq < 16; ++kq){
      float wr[4][4], pr[4][4];
      #pragma unroll
      for (int i = 0; i < 4; ++i) *(float4*)wr[i] = wS[(ot*4+i)*17 + kq];
      #pragma unroll
      for (int jj = 0; jj < 4; ++jj) *(float4*)pr[jj] = pS[(ltl+16*jj)*17 + kq];
      #pragma unroll
      for (int e = 0; e < 4; ++e)
        #pragma unroll
        for (int i = 0; i < 4; ++i)
          #pragma unroll
          for (int jj = 0; jj < 4; ++jj)
            acc[i][half*4 + jj] = __builtin_fmaf(pr[jj][e], wr[i][e], acc[i][half*4 + jj]);
    }
  }
  // store lt (identical addresses/values to r10)
  #pragma unroll
  for (int i = 0; i < 4; ++i){
    int o = oh*64 + ot*4 + i;
    float* dst = lt + ((size_t)((n*9+g)*128 + o))*1024 + lq*128 + ltl;
    #pragma unroll
    for (int j = 0; j < 8; ++j) dst[16*j] = acc[i][j];
  }
  // f64 partials: s1 = sum(tv) (identical j-order), s2 = sum(tv^2) (exact)
  double ps1[4], ps2[4];
  #pragma unroll
  for (int i = 0; i < 4; ++i){
    double s1 = 0.0, s2 = 0.0;
    #pragma unroll
    for (int j = 0; j < 8; ++j){
      double d = (double)acc[i][j];
      s1 += d;
      s2 += d * d;
    }
    ps1[i] = s1; ps2[i] = s2;
  }
  __syncthreads();                 // done reading pS; reuse as f64 scratch
  double* red = (double*)pS;       // 64 rows x 16 = 8 KB
  #pragma unroll
  for (int i = 0; i < 4; ++i) red[(ot*4+i)*16 + ltl] = ps1[i];
  __syncthreads();
  if (t < 64){
    double s = 0.0;
    #pragma unroll
    for (int q = 0; q < 16; ++q) s += red[t*16 + q];    // q-ascending, as r10
    part[((size_t)g*128 + oh*64 + t)*256 + n*8 + lq] = s;
  }
  __syncthreads();
  #pragma unroll
  for (int i = 0; i < 4; ++i) red[(ot*4+i)*16 + ltl] = ps2[i];
  __syncthreads();
  if (t < 64){
    double s = 0.0;
    #pragma unroll
    for (int q = 0; q < 16; ++q) s += red[t*16 + q];
    part2[((size_t)g*128 + oh*64 + t)*256 + n*8 + lq] = s;
  }
}

// ================= K_DEN: mean (bit-identical order) + var via expansion ===========
__global__ __launch_bounds__(64) void k_den(const double* __restrict__ part,
        const double* __restrict__ part2, float* __restrict__ mv){
  __shared__ double redm[64];
  __shared__ double redv[64];
  int go = blockIdx.x, t = threadIdx.x;
  double s = 0.0;
  for (int idx = t; idx < 256; idx += 64) s += part[(size_t)go*256 + idx];
  redm[t] = s;
  double v = 0.0;
  for (int idx = t; idx < 256; idx += 64) v += part2[(size_t)go*256 + idx];
  redv[t] = v;
  __syncthreads();
  for (int k = 32; k > 0; k >>= 1){
    if (t < k){ redm[t] += redm[t+k]; redv[t] += redv[t+k]; }
    __syncthreads();
  }
  if (t == 0){
    float mean = (float)(redm[0] / 32768.0);
    mv[go*2] = mean;
    double m = (double)mean;
    double var64 = (redv[0] - 2.0*m*redm[0] + 32768.0*m*m) / 32768.0;
    float varf = (float)var64;
    mv[go*2 + 1] = __builtin_sqrtf(varf + 1e-5f);
  }
}

// ================= K_OUT (r3 structure verbatim — best measured: 128 us) ============
__global__ __launch_bounds__(256) void k_out_fast(const float* __restrict__ lt,
        const float* __restrict__ mv, const uint32_t* __restrict__ keys,
        const float* __restrict__ gamma, const float* __restrict__ beta,
        float* __restrict__ out){
  #pragma clang fp contract(off)
  __shared__ float    mvL[18];
  __shared__ uint32_t kL[18];
  int bi = blockIdx.x;                  // 4096 = 8 b * 128 o * 4 lc
  int lc = bi & 3, o = (bi >> 2) & 127, b = bi >> 9;
  int t = threadIdx.x;
  if (t < 18){ mvL[t] = mv[((t>>1)*128 + o)*2 + (t&1)]; kL[t] = keys[t]; }
  __syncthreads();
  int l = lc*256 + t;
  float gma = gamma[o], bta = beta[o];
  float S[4] = {0.0f, 0.0f, 0.0f, 0.0f};
  for (int g = 0; g < 9; ++g){
    float rnd[4];
#if PRNG_PARTITIONABLE
    #pragma unroll
    for (int a = 0; a < 4; ++a){
      uint32_t m = (uint32_t)((a*8 + b)*131072 + o*1024 + l);
      uint32_t x0 = 0u, x1 = m;
      threefry2x32(kL[2*g], kL[2*g+1], x0, x1);
      rnd[a] = bits_to_unit(x0 ^ x1);
    }
#else
    #pragma unroll
    for (int a01 = 0; a01 < 2; ++a01){
      uint32_t m = (uint32_t)((a01*8 + b)*131072 + o*1024 + l);
      uint32_t x0 = m, x1 = m + 2097152u;
      threefry2x32(kL[2*g], kL[2*g+1], x0, x1);
      rnd[a01]     = bits_to_unit(x0);
      rnd[a01 + 2] = bits_to_unit(x1);
    }
#endif
    float mean = mvL[2*g], den = mvL[2*g+1];
    #pragma unroll
    for (int a = 0; a < 4; ++a){
      int n = a*8 + b;
      float tv = lt[((size_t)((n*9+g)*128 + o)) * 1024 + l];
      float normed = (tv - mean) / den * gma + bta;
      float th = xla_tanh_f32(4.0f * normed);
      float dec = (th > rnd[a]) ? 1.0f : -1.0f;
      if (normed == 0.0f) dec = 0.0f;
      float cc  = __builtin_fminf(__builtin_fmaxf(normed, -1.0f), 1.0f);
      float fwd = cc + (dec - cc);
      float pre = fwd / 9.0f;
      S[a] = S[a] + pre;
    }
  }
  float z = S[0] * 0.5f;
  z = z + S[1] * 0.25f;
  z = z + S[2] * 0.125f;
  z = z + S[3] * 0.0625f;
  out[(b*128 + o)*1024 + l] = z;
}

// ================= fallback (r1, slow but verified) =================
__global__ __launch_bounds__(256) void k_stats_slow(const float* __restrict__ qw,
        const unsigned long long* __restrict__ sgn, const unsigned long long* __restrict__ dimw,
        float* __restrict__ mv){
  #pragma clang fp contract(off)
  __shared__ double red[256];
  int g = blockIdx.x >> 7, o = blockIdx.x & 127, t = threadIdx.x;
  float wr[64];
  #pragma unroll
  for (int k = 0; k < 64; ++k) wr[k] = qw[(g*128 + o)*64 + k];
  double s1 = 0.0;
  for (int n = 0; n < 32; ++n){
    const unsigned long long* sp = sgn  + (n*9 + g)*1024;
    const unsigned long long* dp = dimw + (n*9 + g)*1024;
    for (int j = 0; j < 4; ++j){
      int l = t + j*256;
      float tvv = dot64(sp[l], dp[l], wr);
      s1 += (double)tvv;
    }
  }
  red[t] = s1; __syncthreads();
  for (int k = 128; k > 0; k >>= 1){ if (t < k) red[t] += red[t+k]; __syncthreads(); }
  float mean = (float)(red[0] / 32768.0);
  __syncthreads();
  double s2 = 0.0;
  for (int n = 0; n < 32; ++n){
    const unsigned long long* sp = sgn  + (n*9 + g)*1024;
    const unsigned long long* dp = dimw + (n*9 + g)*1024;
    for (int j = 0; j < 4; ++j){
      int l = t + j*256;
      float tvv = dot64(sp[l], dp[l], wr);
      float c = tvv - mean;
      float sq = c * c;
      s2 += (double)sq;
    }
  }
  red[t] = s2; __syncthreads();
  for (int k = 128; k > 0; k >>= 1){ if (t < k) red[t] += red[t+k]; __syncthreads(); }
  if (t == 0){
    float var = (float)(red[0] / 32768.0);
    float den = __builtin_sqrtf(var + 1e-5f);
    mv[(g*128+o)*2]   = mean;
    mv[(g*128+o)*2+1] = den;
  }
}

__global__ __launch_bounds__(256) void k_out_slow(const float* __restrict__ qw,
        const unsigned long long* __restrict__ sgn, const unsigned long long* __restrict__ dimw,
        const float* __restrict__ mv, const uint32_t* __restrict__ keys,
        const float* __restrict__ gamma, const float* __restrict__ beta,
        float* __restrict__ out){
  #pragma clang fp contract(off)
  __shared__ float    wv[576];
  __shared__ float    mvL[18];
  __shared__ uint32_t kL[18];
  int bi = blockIdx.x;
  int lc = bi & 3, o = (bi >> 2) & 127, b = bi >> 9;
  int t = threadIdx.x;
  for (int j = t; j < 576; j += 256) wv[j] = qw[((j >> 6)*128 + o)*64 + (j & 63)];
  if (t < 18){ mvL[t] = mv[((t>>1)*128 + o)*2 + (t&1)]; kL[t] = keys[t]; }
  __syncthreads();
  int l = lc*256 + t;
  float gma = gamma[o], bta = beta[o];
  float S[4] = {0.0f, 0.0f, 0.0f, 0.0f};
  for (int g = 0; g < 9; ++g){
    float rnd[4];
#if PRNG_PARTITIONABLE
    #pragma unroll
    for (int a = 0; a < 4; ++a){
      uint32_t m = (uint32_t)((a*8 + b)*131072 + o*1024 + l);
      uint32_t x0 = 0u, x1 = m;
      threefry2x32(kL[2*g], kL[2*g+1], x0, x1);
      rnd[a] = bits_to_unit(x0 ^ x1);
    }
#else
    #pragma unroll
    for (int a01 = 0; a01 < 2; ++a01){
      uint32_t m = (uint32_t)((a01*8 + b)*131072 + o*1024 + l);
      uint32_t x0 = m, x1 = m + 2097152u;
      threefry2x32(kL[2*g], kL[2*g+1], x0, x1);
      rnd[a01]     = bits_to_unit(x0);
      rnd[a01 + 2] = bits_to_unit(x1);
    }
#endif
    float mean = mvL[2*g], den = mvL[2*g+1];
    float wr[64];
    #pragma unroll
    for (int k = 0; k < 64; ++k) wr[k] = wv[g*64 + k];
    #pragma unroll
    for (int a = 0; a < 4; ++a){
      int n = a*8 + b;
      float tvv = dot64(sgn[(n*9+g)*1024 + l], dimw[(n*9+g)*1024 + l], wr);
      float normed = (tvv - mean) / den * gma + bta;
      float th = xla_tanh_f32(4.0f * normed);
      float dec = (th > rnd[a]) ? 1.0f : -1.0f;
      if (normed == 0.0f) dec = 0.0f;
      float cc  = __builtin_fminf(__builtin_fmaxf(normed, -1.0f), 1.0f);
      float fwd = cc + (dec - cc);
      float pre = fwd / 9.0f;
      S[a] = S[a] + pre;
    }
  }
  float z = S[0] * 0.5f;
  z = z + S[1] * 0.25f;
  z = z + S[2] * 0.125f;
  z = z + S[3] * 0.0625f;
  out[(b*128 + o)*1024 + l] = z;
}

extern "C" void kernel_launch(void* const* d_in, const int* in_sizes, int n_in,
                              void* d_out, int out_size, void* d_ws, size_t ws_size,
                              hipStream_t stream){
  (void)in_sizes; (void)n_in; (void)out_size;
  const float* inp   = (const float*)d_in[0];
  const float* wgt   = (const float*)d_in[1];
  const float* gamma = (const float*)d_in[2];
  const float* beta  = (const float*)d_in[3];
  float* out = (float*)d_out;
  char* ws = (char*)d_ws;
  float*              qw    = (float*)(ws + QW_OFF);
  unsigned long long* sgn   = (unsigned long long*)(ws + SGN_OFF);
  unsigned long long* dimw  = (unsigned long long*)(ws + DIM_OFF);
  uint32_t*           keys  = (uint32_t*)(ws + KEYS_OFF);
  float*              mv    = (float*)(ws + MV_OFF);
  float*              lt    = (float*)(ws + LT_OFF);
  double*             part  = (double*)(ws + PART_OFF);
  double*             part2 = (double*)(ws + PART2_OFF);

  hipLaunchKernelGGL(k_front, dim3(416), dim3(256), 0, stream, inp, wgt, qw, keys, sgn, dimw);
  if (ws_size >= (size_t)WS_NEEDED_FAST){
    hipLaunchKernelGGL(k_gemm,     dim3(16, 9, 32), dim3(256), 0, stream, qw, sgn, dimw,
                       lt, part, part2);
    hipLaunchKernelGGL(k_den,      dim3(1152),      dim3(64),  0, stream, part, part2, mv);
    hipLaunchKernelGGL(k_out_fast, dim3(4096),      dim3(256), 0, stream, lt, mv, keys,
                       gamma, beta, out);
  } else {
    hipLaunchKernelGGL(k_stats_slow, dim3(1152), dim3(256), 0, stream, qw, sgn, dimw, mv);
    hipLaunchKernelGGL(k_out_slow,   dim3(4096), dim3(256), 0, stream, qw, sgn, dimw, mv, keys,
                       gamma, beta, out);
  }
}

// Round 12
// 265.674 us; speedup vs baseline: 1.4303x; 1.4303x over previous
//
#include <hip/hip_runtime.h>
#include <stdint.h>

// ---- PRNG mode: 1 = jax_threefry_partitionable (default in jax >= 0.5)
#ifndef PRNG_PARTITIONABLE
#define PRNG_PARTITIONABLE 1
#endif

#define ONE_M_U 0.99999994039535522461f   // 1 - 2^-24 (0x3F7FFFFF)

// ---------------- threefry2x32 (exact JAX rounds) ----------------
__device__ __forceinline__ void tf_4a(uint32_t& x0, uint32_t& x1){
  x0 += x1; x1 = (x1<<13)|(x1>>19); x1 ^= x0;
  x0 += x1; x1 = (x1<<15)|(x1>>17); x1 ^= x0;
  x0 += x1; x1 = (x1<<26)|(x1>>6);  x1 ^= x0;
  x0 += x1; x1 = (x1<<6) |(x1>>26); x1 ^= x0;
}
__device__ __forceinline__ void tf_4b(uint32_t& x0, uint32_t& x1){
  x0 += x1; x1 = (x1<<17)|(x1>>15); x1 ^= x0;
  x0 += x1; x1 = (x1<<29)|(x1>>3);  x1 ^= x0;
  x0 += x1; x1 = (x1<<16)|(x1>>16); x1 ^= x0;
  x0 += x1; x1 = (x1<<24)|(x1>>8);  x1 ^= x0;
}
__device__ __forceinline__ void threefry2x32(uint32_t k0, uint32_t k1, uint32_t& x0, uint32_t& x1){
  uint32_t k2 = k0 ^ k1 ^ 0x1BD11BDAu;
  x0 += k0; x1 += k1;
  tf_4a(x0,x1); x0 += k1; x1 += k2 + 1u;
  tf_4b(x0,x1); x0 += k2; x1 += k0 + 2u;
  tf_4a(x0,x1); x0 += k0; x1 += k1 + 3u;
  tf_4b(x0,x1); x0 += k1; x1 += k2 + 4u;
  tf_4a(x0,x1); x0 += k2; x1 += k0 + 5u;
}

__device__ __forceinline__ float bits_to_unit(uint32_t b){
  #pragma clang fp contract(off)
  float f = __uint_as_float((b >> 9) | 0x3f800000u) - 1.0f;
  float r = f * 2.0f + (-1.0f);
  return __builtin_fmaxf(-1.0f, r);
}

// XLA elemental_ir_emitter EmitTanh f32 (unfused mul/add)
__device__ __forceinline__ float xla_tanh_f32(float x){
  #pragma clang fp contract(off)
  float ax = __builtin_fabsf(x);
  float xc = __builtin_fminf(__builtin_fmaxf(x, -9.0f), 9.0f);
  float x2 = xc * xc;
  float nm = -2.76076847742355e-16f;
  nm = x2 * nm + 2.00018790482477e-13f;
  nm = x2 * nm + -8.60467152213735e-11f;
  nm = x2 * nm + 5.12229709037114e-08f;
  nm = x2 * nm + 1.48572235717979e-05f;
  nm = x2 * nm + 6.37261928875436e-04f;
  nm = x2 * nm + 4.89352455891786e-03f;
  nm = xc * nm;
  float dn = 1.19825839466702e-06f;
  dn = x2 * dn + 1.18534705686654e-04f;
  dn = x2 * dn + 2.26843463243900e-03f;
  dn = x2 * dn + 4.89352518554385e-03f;
  float res = nm / dn;
  return (ax < 0.0004f) ? x : res;
}

// k-ascending fma chain (fallback path only)
__device__ __forceinline__ float dot64(unsigned long long sw, unsigned long long dw,
                                       const float* w){
  float acc = 0.0f;
  #pragma unroll
  for (int k = 0; k < 64; ++k){
    float mag = ((dw >> k) & 1ull) ? ONE_M_U : 1.0f;
    float p   = ((sw >> k) & 1ull) ? mag : -mag;
    acc = __builtin_fmaf(p, w[k], acc);
  }
  return acc;
}

// -------- workspace layout (bytes) --------
#define QW_OFF   0u           // float[9][128][64]   ([g][o][k])
#define SGN_OFF  294912u      // u64[32][9][1024]
#define DIM_OFF  2654208u     // u64[32][9][1024]
#define KEYS_OFF 5013504u     // u32[18]
#define MV_OFF   5013632u     // float[9*128][2]
#define LT_OFF   5023744u     // float[32][9][128][1024]  (fast path)
#define LT_BYTES 150994944u
#define PART_OFF  (LT_OFF + LT_BYTES)       // double[9*128][256]  (sum tv partials)
#define PART_BYTES 2359296u
#define PART2_OFF (PART_OFF + PART_BYTES)   // double[9*128][256]  (sum tv^2 partials)
#define WS_NEEDED_FAST (PART2_OFF + PART_BYTES)

// ================= K_FRONT: blocks 0..287 = stream, 288..415 = weights+keys ========
__global__ __launch_bounds__(256) void k_front(const float* __restrict__ X,
        const float* __restrict__ W, float* __restrict__ qw, uint32_t* __restrict__ keys,
        unsigned long long* __restrict__ sgn, unsigned long long* __restrict__ dimw){
  #pragma clang fp contract(off)
  __shared__ float  bwL[576];
  __shared__ double red[64];
  int bx = blockIdx.x;
  int t = threadIdx.x;
  if (bx < 288){
    // ---- stream path (identical per-thread work to verified k_stream) ----
    int g = bx >> 5;                       // 0..8, block-uniform
    int tid = (bx & 31) * 256 + t;         // 0..8191
    int b = tid >> 10, l = tid & 1023;
    int h = l >> 5, w = l & 31;
    unsigned long long sw0=0ull, sw1=0ull, sw2=0ull, sw3=0ull;
    unsigned long long dw0=0ull, dw1=0ull, dw2=0ull, dw3=0ull;
    const float* Xb = X + b*64*1024;
    int ck0 = g*64;
    #pragma unroll
    for (int i = 0; i < 64; ++i){
      int ck = ck0 + i;
      int c = ck / 9, kp = ck % 9;          // block-uniform -> scalar
      int di = kp / 3 - 1, dj = kp % 3 - 1;
      int hh = h + di, ww = w + dj;
      float v = 0.0f;
      if (hh >= 0 && hh < 32 && ww >= 0 && ww < 32)
        v = Xb[(c*32 + hh)*32 + ww];
      float x = __builtin_fminf(__builtin_fmaxf(v, -1.0f), 1.0f);
      float r = x;
      {
        float sv = (r >= 0.0f) ? 1.0f : -1.0f;
        float d  = sv - x; float p = x + d;
        if (sv > 0.0f) sw0 |= (1ull << i);
        if (__builtin_fabsf(p) < 1.0f) dw0 |= (1ull << i);
        r = r - sv * 0.5f;
      }
      {
        float sv = (r >= 0.0f) ? 1.0f : -1.0f;
        float d  = sv - x; float p = x + d;
        if (sv > 0.0f) sw1 |= (1ull << i);
        if (__builtin_fabsf(p) < 1.0f) dw1 |= (1ull << i);
        r = r - sv * 0.25f;
      }
      {
        float sv = (r >= 0.0f) ? 1.0f : -1.0f;
        float d  = sv - x; float p = x + d;
        if (sv > 0.0f) sw2 |= (1ull << i);
        if (__builtin_fabsf(p) < 1.0f) dw2 |= (1ull << i);
        r = r - sv * 0.125f;
      }
      {
        float sv = (r >= 0.0f) ? 1.0f : -1.0f;
        float d  = sv - x; float p = x + d;
        if (sv > 0.0f) sw3 |= (1ull << i);
        if (__builtin_fabsf(p) < 1.0f) dw3 |= (1ull << i);
        r = r - sv * 0.0625f;
      }
    }
    sgn [((0*8+b)*9 + g)*1024 + l] = sw0;
    sgn [((1*8+b)*9 + g)*1024 + l] = sw1;
    sgn [((2*8+b)*9 + g)*1024 + l] = sw2;
    sgn [((3*8+b)*9 + g)*1024 + l] = sw3;
    dimw[((0*8+b)*9 + g)*1024 + l] = dw0;
    dimw[((1*8+b)*9 + g)*1024 + l] = dw1;
    dimw[((2*8+b)*9 + g)*1024 + l] = dw2;
    dimw[((3*8+b)*9 + g)*1024 + l] = dw3;
  } else {
    // ---- weights path: o = bx-288; f64 reductions use the verified 64-thread order
    int o = bx - 288;
    if (t < 64){
      double s = 0.0;
      for (int j = t; j < 576; j += 64) s += (double)W[o*576 + j];
      red[t] = s;
    }
    __syncthreads();
    for (int k = 32; k > 0; k >>= 1){ if (t < k) red[t] += red[t+k]; __syncthreads(); }
    float mean1 = (float)(red[0] / 576.0);
    __syncthreads();
    for (int j = t; j < 576; j += 256) bwL[j] = W[o*576 + j] - mean1;   // elementwise, exact
    __syncthreads();
    if (t < 64){
      double s = 0.0;
      for (int j = t; j < 576; j += 64) s += (double)bwL[j];
      red[t] = s;
    }
    __syncthreads();
    for (int k = 32; k > 0; k >>= 1){ if (t < k) red[t] += red[t+k]; __syncthreads(); }
    float mean2 = (float)(red[0] / 576.0);
    __syncthreads();
    if (t < 64){
      double s = 0.0;
      for (int j = t; j < 576; j += 64){ float c = bwL[j] - mean2; float sq = c * c; s += (double)sq; }
      red[t] = s;
    }
    __syncthreads();
    for (int k = 32; k > 0; k >>= 1){ if (t < k) red[t] += red[t+k]; __syncthreads(); }
    float varf = (float)(red[0] / 575.0);
    float stdv = __builtin_sqrtf(varf);
    __syncthreads();
    for (int j = t; j < 576; j += 256){       // elementwise, exact
      float b2 = bwL[j] / stdv;
      float c  = __builtin_fminf(__builtin_fmaxf(b2, -1.0f), 1.0f);
      float q  = __builtin_rintf(c * 7.0f) / 7.0f;
      float fwd = c + (q - c);
      int g = j >> 6, k = j & 63;
      qw [(g*128 + o)*64 + k] = fwd;
    }
    if (o == 0 && t == 0){
#if PRNG_PARTITIONABLE
      for (int g = 0; g < 9; ++g){
        uint32_t x0 = 0u, x1 = (uint32_t)g;
        threefry2x32(0u, 42u, x0, x1);
        keys[2*g] = x0; keys[2*g+1] = x1;
      }
#else
      uint32_t outv[18];
      for (int i = 0; i < 9; ++i){
        uint32_t x0 = (uint32_t)i, x1 = (uint32_t)(9 + i);
        threefry2x32(0u, 42u, x0, x1);
        outv[i] = x0; outv[9+i] = x1;
      }
      for (int j = 0; j < 18; ++j) keys[j] = outv[j];
#endif
    }
  }
}

// ================= K_GEMM v5 (r10 verbatim — best measured): 4o x 8l tiles,
//                  64 o per block, 52 KB LDS (3 blocks/CU), dual f64 partials ======
// grid (16, 9, 32): bx = lq(0..7) + 8*oh(0..1). Per-(o,l) FMA chain k-ascending
// 0..63 and f64 partial-tree order identical to r8-r10 -> lt/part/part2 bit-identical.
__global__ __launch_bounds__(256) void k_gemm(const float* __restrict__ qw,
        const unsigned long long* __restrict__ sgn, const unsigned long long* __restrict__ dimw,
        float* __restrict__ lt, double* __restrict__ part, double* __restrict__ part2){
  __shared__ float4 wS[64*17];    // 17408 B: wS[oo*17+kq] = w[g][oh*64+oo][4kq..]
  __shared__ float4 pS[128*17];   // 34816 B: pS[l*17+kq]; reused as f64 red (16 KB)
  int bx = blockIdx.x, g = blockIdx.y, n = blockIdx.z;
  int lq = bx & 7, oh = bx >> 3;
  int t = threadIdx.x;
  // stage w (64 o rows)
  {
    int orow = t >> 4, kq = t & 15;
    const float4* qw4 = (const float4*)qw;
    #pragma unroll
    for (int i = 0; i < 4; ++i){
      int oo = orow + 16*i;
      wS[oo*17 + kq] = qw4[(g*128 + oh*64 + oo)*16 + kq];
    }
  }
  // decode p (v2 verbatim): thread t -> l = t>>1, k-half = t&1
  {
    int l = t >> 1, kh = t & 1;
    unsigned long long sw = sgn [(n*9+g)*1024 + lq*128 + l];
    unsigned long long dw = dimw[(n*9+g)*1024 + lq*128 + l];
    #pragma unroll
    for (int kq = 0; kq < 8; ++kq){
      int kqq = kh*8 + kq;
      float4 v;
      {
        int k = kqq*4;
        float m0 = ((dw>>k)&1ull)?ONE_M_U:1.0f;     v.x = ((sw>>k)&1ull)?m0:-m0;
        float m1 = ((dw>>(k+1))&1ull)?ONE_M_U:1.0f; v.y = ((sw>>(k+1))&1ull)?m1:-m1;
        float m2 = ((dw>>(k+2))&1ull)?ONE_M_U:1.0f; v.z = ((sw>>(k+2))&1ull)?m2:-m2;
        float m3 = ((dw>>(k+3))&1ull)?ONE_M_U:1.0f; v.w = ((sw>>(k+3))&1ull)?m3:-m3;
      }
      pS[l*17 + kqq] = v;
    }
  }
  __syncthreads();
  int ot = t >> 4, ltl = t & 15;     // ot 0..15 -> o = oh*64 + ot*4 + i
  float acc[4][8];
  #pragma unroll
  for (int i = 0; i < 4; ++i)
    #pragma unroll
    for (int j = 0; j < 8; ++j) acc[i][j] = 0.0f;
  for (int kq = 0; kq < 16; ++kq){
    float wr[4][4], pr[8][4];
    #pragma unroll
    for (int i = 0; i < 4; ++i) *(float4*)wr[i] = wS[(ot*4+i)*17 + kq];
    #pragma unroll
    for (int j = 0; j < 8; ++j) *(float4*)pr[j] = pS[(ltl+16*j)*17 + kq];
    #pragma unroll
    for (int e = 0; e < 4; ++e)
      #pragma unroll
      for (int i = 0; i < 4; ++i)
        #pragma unroll
        for (int j = 0; j < 8; ++j)
          acc[i][j] = __builtin_fmaf(pr[j][e], wr[i][e], acc[i][j]);
  }
  // store lt
  #pragma unroll
  for (int i = 0; i < 4; ++i){
    int o = oh*64 + ot*4 + i;
    float* dst = lt + ((size_t)((n*9+g)*128 + o))*1024 + lq*128 + ltl;
    #pragma unroll
    for (int j = 0; j < 8; ++j) dst[16*j] = acc[i][j];
  }
  // f64 partials: s1 = sum(tv) (identical j-order), s2 = sum(tv^2) (exact)
  double ps1[4], ps2[4];
  #pragma unroll
  for (int i = 0; i < 4; ++i){
    double s1 = 0.0, s2 = 0.0;
    #pragma unroll
    for (int j = 0; j < 8; ++j){
      double d = (double)acc[i][j];
      s1 += d;
      s2 += d * d;
    }
    ps1[i] = s1; ps2[i] = s2;
  }
  __syncthreads();                 // done reading pS; reuse as f64 scratch
  double* red = (double*)pS;       // 64 rows x 16 = 8 KB
  #pragma unroll
  for (int i = 0; i < 4; ++i) red[(ot*4+i)*16 + ltl] = ps1[i];
  __syncthreads();
  if (t < 64){
    double s = 0.0;
    #pragma unroll
    for (int q = 0; q < 16; ++q) s += red[t*16 + q];    // q-ascending, as r8-r10
    part[((size_t)g*128 + oh*64 + t)*256 + n*8 + lq] = s;
  }
  __syncthreads();
  #pragma unroll
  for (int i = 0; i < 4; ++i) red[(ot*4+i)*16 + ltl] = ps2[i];
  __syncthreads();
  if (t < 64){
    double s = 0.0;
    #pragma unroll
    for (int q = 0; q < 16; ++q) s += red[t*16 + q];
    part2[((size_t)g*128 + oh*64 + t)*256 + n*8 + lq] = s;
  }
}

// ================= K_DEN: mean (bit-identical order) + var via expansion ===========
__global__ __launch_bounds__(64) void k_den(const double* __restrict__ part,
        const double* __restrict__ part2, float* __restrict__ mv){
  __shared__ double redm[64];
  __shared__ double redv[64];
  int go = blockIdx.x, t = threadIdx.x;
  double s = 0.0;
  for (int idx = t; idx < 256; idx += 64) s += part[(size_t)go*256 + idx];
  redm[t] = s;
  double v = 0.0;
  for (int idx = t; idx < 256; idx += 64) v += part2[(size_t)go*256 + idx];
  redv[t] = v;
  __syncthreads();
  for (int k = 32; k > 0; k >>= 1){
    if (t < k){ redm[t] += redm[t+k]; redv[t] += redv[t+k]; }
    __syncthreads();
  }
  if (t == 0){
    float mean = (float)(redm[0] / 32768.0);
    mv[go*2] = mean;
    double m = (double)mean;
    double var64 = (redv[0] - 2.0*m*redm[0] + 32768.0*m*m) / 32768.0;
    float varf = (float)var64;
    mv[go*2 + 1] = __builtin_sqrtf(varf + 1e-5f);
  }
}

// ================= K_OUT (r3 structure verbatim — best measured: 128 us) ============
__global__ __launch_bounds__(256) void k_out_fast(const float* __restrict__ lt,
        const float* __restrict__ mv, const uint32_t* __restrict__ keys,
        const float* __restrict__ gamma, const float* __restrict__ beta,
        float* __restrict__ out){
  #pragma clang fp contract(off)
  __shared__ float    mvL[18];
  __shared__ uint32_t kL[18];
  int bi = blockIdx.x;                  // 4096 = 8 b * 128 o * 4 lc
  int lc = bi & 3, o = (bi >> 2) & 127, b = bi >> 9;
  int t = threadIdx.x;
  if (t < 18){ mvL[t] = mv[((t>>1)*128 + o)*2 + (t&1)]; kL[t] = keys[t]; }
  __syncthreads();
  int l = lc*256 + t;
  float gma = gamma[o], bta = beta[o];
  float S[4] = {0.0f, 0.0f, 0.0f, 0.0f};
  for (int g = 0; g < 9; ++g){
    float rnd[4];
#if PRNG_PARTITIONABLE
    #pragma unroll
    for (int a = 0; a < 4; ++a){
      uint32_t m = (uint32_t)((a*8 + b)*131072 + o*1024 + l);
      uint32_t x0 = 0u, x1 = m;
      threefry2x32(kL[2*g], kL[2*g+1], x0, x1);
      rnd[a] = bits_to_unit(x0 ^ x1);
    }
#else
    #pragma unroll
    for (int a01 = 0; a01 < 2; ++a01){
      uint32_t m = (uint32_t)((a01*8 + b)*131072 + o*1024 + l);
      uint32_t x0 = m, x1 = m + 2097152u;
      threefry2x32(kL[2*g], kL[2*g+1], x0, x1);
      rnd[a01]     = bits_to_unit(x0);
      rnd[a01 + 2] = bits_to_unit(x1);
    }
#endif
    float mean = mvL[2*g], den = mvL[2*g+1];
    #pragma unroll
    for (int a = 0; a < 4; ++a){
      int n = a*8 + b;
      float tv = lt[((size_t)((n*9+g)*128 + o)) * 1024 + l];
      float normed = (tv - mean) / den * gma + bta;
      float th = xla_tanh_f32(4.0f * normed);
      float dec = (th > rnd[a]) ? 1.0f : -1.0f;
      if (normed == 0.0f) dec = 0.0f;
      float cc  = __builtin_fminf(__builtin_fmaxf(normed, -1.0f), 1.0f);
      float fwd = cc + (dec - cc);
      float pre = fwd / 9.0f;
      S[a] = S[a] + pre;
    }
  }
  float z = S[0] * 0.5f;
  z = z + S[1] * 0.25f;
  z = z + S[2] * 0.125f;
  z = z + S[3] * 0.0625f;
  out[(b*128 + o)*1024 + l] = z;
}

// ================= fallback (r1, slow but verified) =================
__global__ __launch_bounds__(256) void k_stats_slow(const float* __restrict__ qw,
        const unsigned long long* __restrict__ sgn, const unsigned long long* __restrict__ dimw,
        float* __restrict__ mv){
  #pragma clang fp contract(off)
  __shared__ double red[256];
  int g = blockIdx.x >> 7, o = blockIdx.x & 127, t = threadIdx.x;
  float wr[64];
  #pragma unroll
  for (int k = 0; k < 64; ++k) wr[k] = qw[(g*128 + o)*64 + k];
  double s1 = 0.0;
  for (int n = 0; n < 32; ++n){
    const unsigned long long* sp = sgn  + (n*9 + g)*1024;
    const unsigned long long* dp = dimw + (n*9 + g)*1024;
    for (int j = 0; j < 4; ++j){
      int l = t + j*256;
      float tvv = dot64(sp[l], dp[l], wr);
      s1 += (double)tvv;
    }
  }
  red[t] = s1; __syncthreads();
  for (int k = 128; k > 0; k >>= 1){ if (t < k) red[t] += red[t+k]; __syncthreads(); }
  float mean = (float)(red[0] / 32768.0);
  __syncthreads();
  double s2 = 0.0;
  for (int n = 0; n < 32; ++n){
    const unsigned long long* sp = sgn  + (n*9 + g)*1024;
    const unsigned long long* dp = dimw + (n*9 + g)*1024;
    for (int j = 0; j < 4; ++j){
      int l = t + j*256;
      float tvv = dot64(sp[l], dp[l], wr);
      float c = tvv - mean;
      float sq = c * c;
      s2 += (double)sq;
    }
  }
  red[t] = s2; __syncthreads();
  for (int k = 128; k > 0; k >>= 1){ if (t < k) red[t] += red[t+k]; __syncthreads(); }
  if (t == 0){
    float var = (float)(red[0] / 32768.0);
    float den = __builtin_sqrtf(var + 1e-5f);
    mv[(g*128+o)*2]   = mean;
    mv[(g*128+o)*2+1] = den;
  }
}

__global__ __launch_bounds__(256) void k_out_slow(const float* __restrict__ qw,
        const unsigned long long* __restrict__ sgn, const unsigned long long* __restrict__ dimw,
        const float* __restrict__ mv, const uint32_t* __restrict__ keys,
        const float* __restrict__ gamma, const float* __restrict__ beta,
        float* __restrict__ out){
  #pragma clang fp contract(off)
  __shared__ float    wv[576];
  __shared__ float    mvL[18];
  __shared__ uint32_t kL[18];
  int bi = blockIdx.x;
  int lc = bi & 3, o = (bi >> 2) & 127, b = bi >> 9;
  int t = threadIdx.x;
  for (int j = t; j < 576; j += 256) wv[j] = qw[((j >> 6)*128 + o)*64 + (j & 63)];
  if (t < 18){ mvL[t] = mv[((t>>1)*128 + o)*2 + (t&1)]; kL[t] = keys[t]; }
  __syncthreads();
  int l = lc*256 + t;
  float gma = gamma[o], bta = beta[o];
  float S[4] = {0.0f, 0.0f, 0.0f, 0.0f};
  for (int g = 0; g < 9; ++g){
    float rnd[4];
#if PRNG_PARTITIONABLE
    #pragma unroll
    for (int a = 0; a < 4; ++a){
      uint32_t m = (uint32_t)((a*8 + b)*131072 + o*1024 + l);
      uint32_t x0 = 0u, x1 = m;
      threefry2x32(kL[2*g], kL[2*g+1], x0, x1);
      rnd[a] = bits_to_unit(x0 ^ x1);
    }
#else
    #pragma unroll
    for (int a01 = 0; a01 < 2; ++a01){
      uint32_t m = (uint32_t)((a01*8 + b)*131072 + o*1024 + l);
      uint32_t x0 = m, x1 = m + 2097152u;
      threefry2x32(kL[2*g], kL[2*g+1], x0, x1);
      rnd[a01]     = bits_to_unit(x0);
      rnd[a01 + 2] = bits_to_unit(x1);
    }
#endif
    float mean = mvL[2*g], den = mvL[2*g+1];
    float wr[64];
    #pragma unroll
    for (int k = 0; k < 64; ++k) wr[k] = wv[g*64 + k];
    #pragma unroll
    for (int a = 0; a < 4; ++a){
      int n = a*8 + b;
      float tvv = dot64(sgn[(n*9+g)*1024 + l], dimw[(n*9+g)*1024 + l], wr);
      float normed = (tvv - mean) / den * gma + bta;
      float th = xla_tanh_f32(4.0f * normed);
      float dec = (th > rnd[a]) ? 1.0f : -1.0f;
      if (normed == 0.0f) dec = 0.0f;
      float cc  = __builtin_fminf(__builtin_fmaxf(normed, -1.0f), 1.0f);
      float fwd = cc + (dec - cc);
      float pre = fwd / 9.0f;
      S[a] = S[a] + pre;
    }
  }
  float z = S[0] * 0.5f;
  z = z + S[1] * 0.25f;
  z = z + S[2] * 0.125f;
  z = z + S[3] * 0.0625f;
  out[(b*128 + o)*1024 + l] = z;
}

extern "C" void kernel_launch(void* const* d_in, const int* in_sizes, int n_in,
                              void* d_out, int out_size, void* d_ws, size_t ws_size,
                              hipStream_t stream){
  (void)in_sizes; (void)n_in; (void)out_size;
  const float* inp   = (const float*)d_in[0];
  const float* wgt   = (const float*)d_in[1];
  const float* gamma = (const float*)d_in[2];
  const float* beta  = (const float*)d_in[3];
  float* out = (float*)d_out;
  char* ws = (char*)d_ws;
  float*              qw    = (float*)(ws + QW_OFF);
  unsigned long long* sgn   = (unsigned long long*)(ws + SGN_OFF);
  unsigned long long* dimw  = (unsigned long long*)(ws + DIM_OFF);
  uint32_t*           keys  = (uint32_t*)(ws + KEYS_OFF);
  float*              mv    = (float*)(ws + MV_OFF);
  float*              lt    = (float*)(ws + LT_OFF);
  double*             part  = (double*)(ws + PART_OFF);
  double*             part2 = (double*)(ws + PART2_OFF);

  hipLaunchKernelGGL(k_front, dim3(416), dim3(256), 0, stream, inp, wgt, qw, keys, sgn, dimw);
  if (ws_size >= (size_t)WS_NEEDED_FAST){
    hipLaunchKernelGGL(k_gemm,     dim3(16, 9, 32), dim3(256), 0, stream, qw, sgn, dimw,
                       lt, part, part2);
    hipLaunchKernelGGL(k_den,      dim3(1152),      dim3(64),  0, stream, part, part2, mv);
    hipLaunchKernelGGL(k_out_fast, dim3(4096),      dim3(256), 0, stream, lt, mv, keys,
                       gamma, beta, out);
  } else {
    hipLaunchKernelGGL(k_stats_slow, dim3(1152), dim3(256), 0, stream, qw, sgn, dimw, mv);
    hipLaunchKernelGGL(k_out_slow,   dim3(4096), dim3(256), 0, stream, qw, sgn, dimw, mv, keys,
                       gamma, beta, out);
  }
}